// Round 16
// baseline (192.433 us; speedup 1.0000x reference)
//
#include <hip/hip_runtime.h>
#include <math.h>

#define NN 50000
#define NE 800000
#define DD 128
#define DOUT 40
#define BN_EPS_F 1e-5f
#define BSTRIDE 32           // bucket row = one 64B line; overflow list for deg>32
#define OVF_MAX 8192
#define NPX (NN / 8)         // 6250 nodes per XCD partition
#define EPB 1024             // edges per chunk: 4 edges/thread via int4
#define BUCKET_BLOCKS (((NE + EPB - 1) / EPB) * 8)   // 6256
#define X2BF_BLOCKS 6250
#define WPREP_BLOCKS ((5 * 16384 + 255) / 256)       // 320
#define NSLOT 8              // BN-stats contention shards
#define HST 136              // h-tile stride (ushorts): 272B rows, 16B-aligned

typedef __attribute__((ext_vector_type(8))) short bf16x8;
typedef __attribute__((ext_vector_type(4))) float f32x4;

static __device__ __forceinline__ unsigned short f2bf(float f) {
  unsigned u = __float_as_uint(f);
  unsigned r = (u + 0x7FFFu + ((u >> 16) & 1u)) >> 16;
  return (unsigned short)r;
}
static __device__ __forceinline__ float bf2f(unsigned short u) {
  return __uint_as_float((unsigned)u << 16);
}

// ---------------- zero cnt + stats + overflow counter ----------------
__global__ void k_zero(int* __restrict__ cnt, float* __restrict__ stats,
                       int* __restrict__ ovfc) {
  int i = blockIdx.x * 256 + threadIdx.x;
  if (i < NN) cnt[i] = 0;
  if (i < 2 * NSLOT * 2 * DD) stats[i] = 0.f;
  if (i == 0) ovfc[0] = 0;
}

// ---- fused: XCD-partitioned bucket build | x->bf16 | weight frag shuffle ----
__global__ void k_bucketprep(const int* __restrict__ srcI, const int* __restrict__ dstI,
                             int* __restrict__ cnt, unsigned short* __restrict__ bkt,
                             int* __restrict__ ovfc, unsigned* __restrict__ ovf,
                             const float4* __restrict__ x, ushort4* __restrict__ xb,
                             const float* __restrict__ W0, const float* __restrict__ W1,
                             const float* __restrict__ W2, const float* __restrict__ W3,
                             const float* __restrict__ W4, unsigned short* __restrict__ wf) {
  int b = blockIdx.x;
  if (b < BUCKET_BLOCKS) {
    int xcd = b & 7;
    int chunk = b >> 3;
    int lo = xcd * NPX, hi = lo + NPX;
    int e0 = chunk * EPB + threadIdx.x * 4;
    if (e0 < NE) {
      int4 d4 = *(const int4*)(dstI + e0);
      int4 s4 = *(const int4*)(srcI + e0);
      int dd[4] = {d4.x, d4.y, d4.z, d4.w};
      int ss[4] = {s4.x, s4.y, s4.z, s4.w};
#pragma unroll
      for (int i = 0; i < 4; i++) {
        int d = dd[i];
        if (d >= lo && d < hi) {
          int r = atomicAdd(&cnt[d], 1);
          if (r < BSTRIDE) {
            bkt[(size_t)d * BSTRIDE + r] = (unsigned short)ss[i];
          } else {
            int o = atomicAdd(ovfc, 1);
            if (o < OVF_MAX) ovf[o] = ((unsigned)d << 16) | (unsigned)ss[i];
          }
        }
      }
    }
  } else if (b < BUCKET_BLOCKS + X2BF_BLOCKS) {
    int i = (b - BUCKET_BLOCKS) * 256 + threadIdx.x;
    if (i < NN * 32) {
      float4 v = x[i];
      ushort4 r;
      r.x = f2bf(v.x); r.y = f2bf(v.y); r.z = f2bf(v.z); r.w = f2bf(v.w);
      xb[i] = r;
    }
  } else {
    int fid = (b - BUCKET_BLOCKS - X2BF_BLOCKS) * 256 + threadIdx.x;
    if (fid >= 5 * 16384) return;
    int g = fid >> 14;
    int r = fid & 16383;
    int i = r & 7;
    int lane = (r >> 3) & 63;
    int ks = (r >> 9) & 3;
    int ct = r >> 11;
    int k = ks * 32 + (lane >> 4) * 8 + i;
    int col = ct * 16 + (lane & 15);
    const float* Wp = (g == 0) ? W0 : (g == 1) ? W1 : (g == 2) ? W2 : (g == 3) ? W3 : W4;
    float w = Wp[k * DD + col];
    wf[g * 16384 + r] = f2bf(w);
  }
}

// ------- fused aggr + GEMM1 + stats: gather (aggr mapping) -> LDS -> MFMA -------
// 64 rows/block, grid 782 (~3 blk/CU x 8 waves = 24 waves/CU keeps gather BW; r9/r15
// lesson: gather needs aggr-style mapping + aggr-level occupancy).
__global__ __launch_bounds__(512) void k_aggemm(
    const unsigned short* __restrict__ in, const int* __restrict__ cnt,
    const unsigned short* __restrict__ bkt,
    const int* __restrict__ ovfc, const unsigned* __restrict__ ovf,
    const unsigned short* __restrict__ wf, const float* __restrict__ bias,
    unsigned short* __restrict__ outB, float* __restrict__ statsOut) {
  __shared__ __align__(16) short lw[16384];            // 32 KB W-hi frags
  __shared__ __align__(16) unsigned short hs[64 * HST];// 17 KB agg tile
  __shared__ float lbias[DD], ls[DD], lq[DD];
  int tid = threadIdx.x;
  int lane = tid & 63, wv = tid >> 6;
  int rbase = blockIdx.x * 64;

  // ---- W staging: 32 KB, 4 float4 per thread ----
  {
    const float4* src = (const float4*)wf;
    float4* dst = (float4*)lw;
#pragma unroll
    for (int it = 0; it < 4; it++) dst[it * 512 + tid] = src[it * 512 + tid];
  }
  if (tid < DD) { lbias[tid] = bias[tid]; ls[tid] = 0.f; lq[tid] = 0.f; }

  // ---- phase 1: gather, 16 lanes/row (aggr mapping), 2 nodes/group ----
  {
    int l16 = tid & 15;
    const unsigned short* base = in + l16 * 8;
#pragma unroll
    for (int rep = 0; rep < 2; rep++) {
      int nl = (tid >> 4) + rep * 32;     // local row 0..63
      int node = rbase + nl;
      float a[8] = {0.f, 0.f, 0.f, 0.f, 0.f, 0.f, 0.f, 0.f};
      if (node < NN) {
        bf16x8 sv = *(const bf16x8*)(base + (size_t)node * DD);
#pragma unroll
        for (int i = 0; i < 8; i++) a[i] = bf2f((unsigned short)sv[i]);
        int cn = cnt[node];
        int ce = (cn < BSTRIDE) ? cn : BSTRIDE;
        const unsigned short* bp = bkt + (size_t)node * BSTRIDE;
        int j = 0;
        for (; j + 3 < ce; j += 4) {
          int s0 = bp[j], s1 = bp[j + 1], s2 = bp[j + 2], s3 = bp[j + 3];
          bf16x8 v0 = *(const bf16x8*)(base + (size_t)s0 * DD);
          bf16x8 v1 = *(const bf16x8*)(base + (size_t)s1 * DD);
          bf16x8 v2 = *(const bf16x8*)(base + (size_t)s2 * DD);
          bf16x8 v3 = *(const bf16x8*)(base + (size_t)s3 * DD);
#pragma unroll
          for (int i = 0; i < 8; i++)
            a[i] += bf2f((unsigned short)v0[i]) + bf2f((unsigned short)v1[i]) +
                    bf2f((unsigned short)v2[i]) + bf2f((unsigned short)v3[i]);
        }
        for (; j < ce; j++) {
          bf16x8 v0 = *(const bf16x8*)(base + (size_t)bp[j] * DD);
#pragma unroll
          for (int i = 0; i < 8; i++) a[i] += bf2f((unsigned short)v0[i]);
        }
        if (cn > BSTRIDE) {
          int no = ovfc[0];
          if (no > OVF_MAX) no = OVF_MAX;
          for (int o = 0; o < no; o++) {
            unsigned pr = ovf[o];
            if ((int)(pr >> 16) == node) {
              bf16x8 v0 = *(const bf16x8*)(base + (size_t)(pr & 0xFFFFu) * DD);
#pragma unroll
              for (int i = 0; i < 8; i++) a[i] += bf2f((unsigned short)v0[i]);
            }
          }
        }
      }
      bf16x8 hv;
#pragma unroll
      for (int i = 0; i < 8; i++) hv[i] = (short)f2bf(a[i]);
      *(bf16x8*)(&hs[nl * HST + l16 * 8]) = hv;
    }
  }
  __syncthreads();

  // ---- phase 2: GEMM. wave wv = rowblk (wv>>1) x colhalf (wv&1), 16 MFMAs ----
  int rblk = wv >> 1, ch = wv & 1;
  int kq = (lane >> 4) * 8;
  bf16x8 araw[4];
  {
    int lr = rblk * 16 + (lane & 15);
#pragma unroll
    for (int ks = 0; ks < 4; ks++)
      araw[ks] = *(const bf16x8*)(&hs[lr * HST + ks * 32 + kq]);
  }
  f32x4 acc[4];
#pragma unroll
  for (int ct = 0; ct < 4; ct++) acc[ct] = (f32x4){0.f, 0.f, 0.f, 0.f};
  const bf16x8* lwv = (const bf16x8*)lw;
#pragma unroll
  for (int ks = 0; ks < 4; ks++) {
#pragma unroll
    for (int ct = 0; ct < 4; ct++) {
      bf16x8 bh = lwv[((ch * 4 + ct) * 4 + ks) * 64 + lane];
      acc[ct] = __builtin_amdgcn_mfma_f32_16x16x32_bf16(araw[ks], bh, acc[ct], 0, 0, 0);
    }
  }

  // ---- epilogue: store h1 + sharded stats ----  C/D: col=lane&15, row=(lane>>4)*4+reg
  {
    int r0 = rbase + rblk * 16 + (lane >> 4) * 4;
#pragma unroll
    for (int ct = 0; ct < 4; ct++) {
      int col = ch * 64 + ct * 16 + (lane & 15);
      float bb = lbias[col];
      float s = 0.f, q = 0.f;
#pragma unroll
      for (int j = 0; j < 4; j++) {
        int row = r0 + j;
        if (row < NN) {
          float v = acc[ct][j] + bb;
          outB[(size_t)row * DD + col] = f2bf(v);
          s += v; q += v * v;
        }
      }
      s += __shfl_xor(s, 16); s += __shfl_xor(s, 32);
      q += __shfl_xor(q, 16); q += __shfl_xor(q, 32);
      if ((lane >> 4) == 0) {
        atomicAdd(&ls[col], s);
        atomicAdd(&lq[col], q);
      }
    }
  }
  __syncthreads();
  if (tid < DD) {
    float* slot = statsOut + (blockIdx.x & (NSLOT - 1)) * 2 * DD;
    atomicAdd(&slot[tid], ls[tid]);
    atomicAdd(&slot[DD + tid], lq[tid]);
  }
}

// ------- MFMA GEMM (BN -> relu -> GEMM -> relu) and fused head ----------
template<bool BN_IN, bool RELU_OUT, bool STATS_OUT, bool HEAD>
__global__ __launch_bounds__(512) void k_mgemm(
    const unsigned short* __restrict__ in, const unsigned short* __restrict__ wf,
    const float* __restrict__ bias, float* __restrict__ outF,
    unsigned short* __restrict__ outB,
    const float* __restrict__ statsIn, float* __restrict__ statsOut,
    const float* __restrict__ gamma, const float* __restrict__ beta,
    const float* __restrict__ W2h, const float* __restrict__ b2h) {
  constexpr int SMEM_BYTES = HEAD ? 54272 : 32768;
  __shared__ __align__(16) char smem[SMEM_BYTES];
  __shared__ float scs[DD], shs[DD], lbias[DD], ls[DD], lq[DD];
  short* lw = (short*)smem;
  int tid = threadIdx.x;
  int lane = tid & 63, wv = tid >> 6;
  int rbase = blockIdx.x * 128 + wv * 16;
  int kq = (lane >> 4) * 8;

  // ---- A prefetch (before W staging to overlap round trips) ----
  bf16x8 araw[4];
  {
    int row = rbase + (lane & 15);
    bool v = row < NN;
    const unsigned short* ap = in + (size_t)row * DD + kq;
    bf16x8 zz = {0, 0, 0, 0, 0, 0, 0, 0};
#pragma unroll
    for (int ks = 0; ks < 4; ks++)
      araw[ks] = v ? *(const bf16x8*)(ap + ks * 32) : zz;
  }

  // ---- W staging: 32 KB, 4 float4 per thread ----
  {
    const float4* src = (const float4*)wf;
    float4* dst = (float4*)lw;
#pragma unroll
    for (int it = 0; it < 4; it++) dst[it * 512 + tid] = src[it * 512 + tid];
  }
  if (tid < DD) {
    lbias[tid] = bias[tid];
    if (STATS_OUT) { ls[tid] = 0.f; lq[tid] = 0.f; }
    if (BN_IN) {
      float su = 0.f, sq = 0.f;
#pragma unroll
      for (int s = 0; s < NSLOT; s++) {
        su += statsIn[s * 2 * DD + tid];
        sq += statsIn[s * 2 * DD + DD + tid];
      }
      float mu  = su * (1.0f / NN);
      float var = sq * (1.0f / NN) - mu * mu;
      float sc  = gamma[tid] * rsqrtf(var + BN_EPS_F);
      scs[tid] = sc;
      shs[tid] = beta[tid] - mu * sc;
    }
  }
  __syncthreads();

  bf16x8 ahi[4];
  if constexpr (BN_IN) {
#pragma unroll
    for (int ks = 0; ks < 4; ks++) {
      const float4* s4 = (const float4*)&scs[ks * 32 + kq];
      const float4* h4 = (const float4*)&shs[ks * 32 + kq];
      float4 sa = s4[0], sb = s4[1], ha = h4[0], hb = h4[1];
      float ss[8] = {sa.x, sa.y, sa.z, sa.w, sb.x, sb.y, sb.z, sb.w};
      float hh[8] = {ha.x, ha.y, ha.z, ha.w, hb.x, hb.y, hb.z, hb.w};
      bf16x8 h;
#pragma unroll
      for (int i = 0; i < 8; i++) {
        float xv = fmaxf(bf2f((unsigned short)araw[ks][i]) * ss[i] + hh[i], 0.f);
        h[i] = (short)f2bf(xv);
      }
      ahi[ks] = h;
    }
  } else {
#pragma unroll
    for (int ks = 0; ks < 4; ks++) ahi[ks] = araw[ks];
  }

  // ---- MFMA main loop: 32 MFMAs/wave ----
  f32x4 acc[8];
#pragma unroll
  for (int ct = 0; ct < 8; ct++) acc[ct] = (f32x4){0.f, 0.f, 0.f, 0.f};
  const bf16x8* lwv = (const bf16x8*)lw;
#pragma unroll
  for (int ks = 0; ks < 4; ks++) {
#pragma unroll
    for (int ct = 0; ct < 8; ct++) {
      bf16x8 bh = lwv[(ct * 4 + ks) * 64 + lane];
      acc[ct] = __builtin_amdgcn_mfma_f32_16x16x32_bf16(ahi[ks], bh, acc[ct], 0, 0, 0);
    }
  }

  // ---- epilogue ----  C/D layout: col = lane&15, row = (lane>>4)*4 + reg
  if constexpr (!HEAD) {
    int r0 = rbase + (lane >> 4) * 4;
#pragma unroll
    for (int ct = 0; ct < 8; ct++) {
      int col = ct * 16 + (lane & 15);
      float bb = lbias[col];
      float s = 0.f, q = 0.f;
#pragma unroll
      for (int j = 0; j < 4; j++) {
        int row = r0 + j;
        if (row < NN) {
          float v = acc[ct][j] + bb;
          if (RELU_OUT) v = fmaxf(v, 0.f);
          outB[(size_t)row * DD + col] = f2bf(v);
          if (STATS_OUT) { s += v; q += v * v; }
        }
      }
      if (STATS_OUT) {
        s += __shfl_xor(s, 16); s += __shfl_xor(s, 32);
        q += __shfl_xor(q, 16); q += __shfl_xor(q, 32);
        if ((lane >> 4) == 0) {
          atomicAdd(&ls[col], s);
          atomicAdd(&lq[col], q);
        }
      }
    }
    if (STATS_OUT) {
      __syncthreads();
      if (tid < DD) {
        float* slot = statsOut + (blockIdx.x & (NSLOT - 1)) * 2 * DD;
        atomicAdd(&slot[tid], ls[tid]);
        atomicAdd(&slot[DD + tid], lq[tid]);
      }
    }
  } else {
    // ---- fused head ----
    unsigned short* hs2 = (unsigned short*)smem;       // [128][132] bf16
    float* W2s = (float*)(smem + 33792);               // [128][40] f32
    __syncthreads();                                   // all waves done reading lw
    {
      int lr0 = wv * 16 + (lane >> 4) * 4;
#pragma unroll
      for (int ct = 0; ct < 8; ct++) {
        int col = ct * 16 + (lane & 15);
        float bb = lbias[col];
#pragma unroll
        for (int j = 0; j < 4; j++) {
          float v = fmaxf(acc[ct][j] + bb, 0.f);
          hs2[(lr0 + j) * 132 + col] = f2bf(v);
        }
      }
      const float4* W2g = (const float4*)W2h;
      float4* W2s4 = (float4*)W2s;
#pragma unroll
      for (int it = 0; it < 3; it++) {
        int idx = it * 512 + tid;
        if (idx < 1280) W2s4[idx] = W2g[idx];
      }
    }
    __syncthreads();
    int lrow = tid >> 2, q = tid & 3;
    int grow = blockIdx.x * 128 + lrow;
    float a2[40];
#pragma unroll
    for (int j = 0; j < 40; j++) a2[j] = 0.f;
    for (int kk = 0; kk < 32; kk++) {
      int k = kk * 4 + q;
      float hv = bf2f(hs2[lrow * 132 + k]);
      const float4* wrow = (const float4*)(W2s + k * DOUT);
#pragma unroll
      for (int j4 = 0; j4 < 10; j4++) {
        float4 w = wrow[j4];
        a2[j4 * 4 + 0] += hv * w.x;
        a2[j4 * 4 + 1] += hv * w.y;
        a2[j4 * 4 + 2] += hv * w.z;
        a2[j4 * 4 + 3] += hv * w.w;
      }
    }
#pragma unroll
    for (int j = 0; j < 40; j++) {
      a2[j] += __shfl_xor(a2[j], 1);
      a2[j] += __shfl_xor(a2[j], 2);
    }
    if (q == 0 && grow < NN) {
      const float4* b24 = (const float4*)b2h;
      float m = -INFINITY;
#pragma unroll
      for (int j4 = 0; j4 < 10; j4++) {
        float4 bb = b24[j4];
        a2[j4 * 4 + 0] += bb.x; a2[j4 * 4 + 1] += bb.y;
        a2[j4 * 4 + 2] += bb.z; a2[j4 * 4 + 3] += bb.w;
      }
#pragma unroll
      for (int j = 0; j < 40; j++) m = fmaxf(m, a2[j]);
      float s = 0.f;
#pragma unroll
      for (int j = 0; j < 40; j++) s += expf(a2[j] - m);
      float d = m + logf(s);
      float4* out4 = (float4*)(outF + (size_t)grow * DOUT);
#pragma unroll
      for (int j4 = 0; j4 < 10; j4++) {
        float4 v = make_float4(a2[j4 * 4 + 0] - d, a2[j4 * 4 + 1] - d,
                               a2[j4 * 4 + 2] - d, a2[j4 * 4 + 3] - d);
        out4[j4] = v;
      }
    }
  }
}

extern "C" void kernel_launch(void* const* d_in, const int* in_sizes, int n_in,
                              void* d_out, int out_size, void* d_ws, size_t ws_size,
                              hipStream_t stream) {
  const float* x   = (const float*)d_in[0];
  const int*   ei  = (const int*)d_in[1];
  const float* W1a = (const float*)d_in[2];
  const float* b1a = (const float*)d_in[3];
  const float* g1  = (const float*)d_in[4];
  const float* be1 = (const float*)d_in[5];
  const float* W2a = (const float*)d_in[6];
  const float* b2a = (const float*)d_in[7];
  const float* W1b = (const float*)d_in[8];
  const float* b1b = (const float*)d_in[9];
  const float* g2  = (const float*)d_in[10];
  const float* be2 = (const float*)d_in[11];
  const float* W2b = (const float*)d_in[12];
  const float* b2b = (const float*)d_in[13];
  const float* Wl1 = (const float*)d_in[14];
  const float* bl1 = (const float*)d_in[15];
  const float* Wl2 = (const float*)d_in[16];
  const float* bl2 = (const float*)d_in[17];
  float* out = (float*)d_out;

  unsigned short* bufX = (unsigned short*)d_ws;           // N x 128 bf16
  unsigned short* bufA = bufX + (size_t)NN * DD;          // N x 128 bf16
  unsigned short* bufB = bufA + (size_t)NN * DD;          // N x 128 bf16
  float* stats1 = (float*)(bufB + (size_t)NN * DD);       // NSLOT x 256
  float* stats2 = stats1 + NSLOT * 2 * DD;                // NSLOT x 256
  int*   cnt    = (int*)(stats2 + NSLOT * 2 * DD);        // N
  int*   ovfc   = cnt + NN;                               // 4 (1 used)
  unsigned* ovf = (unsigned*)(ovfc + 4);                  // OVF_MAX
  unsigned short* bkt = (unsigned short*)(ovf + OVF_MAX); // N x BSTRIDE
  size_t wfOff = (((size_t)(bkt + (size_t)NN * BSTRIDE) - (size_t)d_ws) + 15) & ~(size_t)15;
  unsigned short* wfrag = (unsigned short*)((char*)d_ws + wfOff);   // 5 x 16384 bf16

  const int* srcI = ei;
  const int* dstI = ei + NE;

  dim3 blk(256);
  int gemmGrid = (NN + 127) / 128;                       // 391
  int agGrid   = (NN + 63) / 64;                         // 782
  int bpGrid   = BUCKET_BLOCKS + X2BF_BLOCKS + WPREP_BLOCKS;
  int zeroGrid = (NN + 255) / 256;

  // ---- setup ----
  k_zero<<<zeroGrid, blk, 0, stream>>>(cnt, stats1, ovfc);
  k_bucketprep<<<bpGrid, blk, 0, stream>>>(srcI, dstI, cnt, bkt, ovfc, ovf,
                                           (const float4*)x, (ushort4*)bufX,
                                           W1a, W2a, W1b, W2b, Wl1, wfrag);

  // ---- conv1: fused aggr+GEMM1+stats, then BN+GEMM2 ----
  k_aggemm<<<agGrid, 512, 0, stream>>>(bufX, cnt, bkt, ovfc, ovf,
                                       wfrag + 0 * 16384, b1a, bufB, stats1);
  k_mgemm<true, true, false, false><<<gemmGrid, 512, 0, stream>>>(
      bufB, wfrag + 1 * 16384, b2a, nullptr, bufA,
      stats1, nullptr, g1, be1, nullptr, nullptr);
  // ---- conv2 ----
  k_aggemm<<<agGrid, 512, 0, stream>>>(bufA, cnt, bkt, ovfc, ovf,
                                       wfrag + 2 * 16384, b1b, bufB, stats2);
  k_mgemm<true, true, false, false><<<gemmGrid, 512, 0, stream>>>(
      bufB, wfrag + 3 * 16384, b2b, nullptr, bufA,
      stats2, nullptr, g2, be2, nullptr, nullptr);
  // ---- fused head ----
  k_mgemm<false, false, false, true><<<gemmGrid, 512, 0, stream>>>(
      bufA, wfrag + 4 * 16384, bl1, out, nullptr,
      nullptr, nullptr, nullptr, nullptr, Wl2, bl2);
}

// Round 17
// 181.784 us; speedup vs baseline: 1.0586x; 1.0586x over previous
//
#include <hip/hip_runtime.h>
#include <math.h>

#define NN 50000
#define NE 800000
#define DD 128
#define DOUT 40
#define BN_EPS_F 1e-5f
#define BSTRIDE 32           // bucket row = one 64B line; overflow list for deg>32
#define OVF_MAX 8192
#define NPX (NN / 8)         // 6250 nodes per XCD partition
#define EPB 1024             // edges per chunk: 4 edges/thread via int4
#define BUCKET_BLOCKS (((NE + EPB - 1) / EPB) * 8)   // 6256
#define X2BF_BLOCKS 6250
#define WPREP_BLOCKS ((5 * 16384 + 255) / 256)       // 320
#define NSLOT 8              // BN-stats contention shards
#define HST 136              // aggemm h-tile stride (ushorts)

typedef __attribute__((ext_vector_type(8))) short bf16x8;
typedef __attribute__((ext_vector_type(4))) float f32x4;

static __device__ __forceinline__ unsigned short f2bf(float f) {
  unsigned u = __float_as_uint(f);
  unsigned r = (u + 0x7FFFu + ((u >> 16) & 1u)) >> 16;
  return (unsigned short)r;
}
static __device__ __forceinline__ float bf2f(unsigned short u) {
  return __uint_as_float((unsigned)u << 16);
}

// ---------------- zero cnt + stats + overflow counter ----------------
__global__ void k_zero(int* __restrict__ cnt, float* __restrict__ stats,
                       int* __restrict__ ovfc) {
  int i = blockIdx.x * 256 + threadIdx.x;
  if (i < NN) cnt[i] = 0;
  if (i < 2 * NSLOT * 2 * DD) stats[i] = 0.f;
  if (i == 0) ovfc[0] = 0;
}

// ---- fused: XCD-partitioned bucket build | x->bf16 | weight frag shuffle ----
__global__ void k_bucketprep(const int* __restrict__ srcI, const int* __restrict__ dstI,
                             int* __restrict__ cnt, unsigned short* __restrict__ bkt,
                             int* __restrict__ ovfc, unsigned* __restrict__ ovf,
                             const float4* __restrict__ x, ushort4* __restrict__ xb,
                             const float* __restrict__ W0, const float* __restrict__ W1,
                             const float* __restrict__ W2, const float* __restrict__ W3,
                             const float* __restrict__ W4, unsigned short* __restrict__ wf) {
  int b = blockIdx.x;
  if (b < BUCKET_BLOCKS) {
    int xcd = b & 7;
    int chunk = b >> 3;
    int lo = xcd * NPX, hi = lo + NPX;
    int e0 = chunk * EPB + threadIdx.x * 4;
    if (e0 < NE) {
      int4 d4 = *(const int4*)(dstI + e0);
      int4 s4 = *(const int4*)(srcI + e0);
      int dd[4] = {d4.x, d4.y, d4.z, d4.w};
      int ss[4] = {s4.x, s4.y, s4.z, s4.w};
#pragma unroll
      for (int i = 0; i < 4; i++) {
        int d = dd[i];
        if (d >= lo && d < hi) {
          int r = atomicAdd(&cnt[d], 1);
          if (r < BSTRIDE) {
            bkt[(size_t)d * BSTRIDE + r] = (unsigned short)ss[i];
          } else {
            int o = atomicAdd(ovfc, 1);
            if (o < OVF_MAX) ovf[o] = ((unsigned)d << 16) | (unsigned)ss[i];
          }
        }
      }
    }
  } else if (b < BUCKET_BLOCKS + X2BF_BLOCKS) {
    int i = (b - BUCKET_BLOCKS) * 256 + threadIdx.x;
    if (i < NN * 32) {
      float4 v = x[i];
      ushort4 r;
      r.x = f2bf(v.x); r.y = f2bf(v.y); r.z = f2bf(v.z); r.w = f2bf(v.w);
      xb[i] = r;
    }
  } else {
    int fid = (b - BUCKET_BLOCKS - X2BF_BLOCKS) * 256 + threadIdx.x;
    if (fid >= 5 * 16384) return;
    int g = fid >> 14;
    int r = fid & 16383;
    int i = r & 7;
    int lane = (r >> 3) & 63;
    int ks = (r >> 9) & 3;
    int ct = r >> 11;
    int k = ks * 32 + (lane >> 4) * 8 + i;
    int col = ct * 16 + (lane & 15);
    const float* Wp = (g == 0) ? W0 : (g == 1) ? W1 : (g == 2) ? W2 : (g == 3) ? W3 : W4;
    float w = Wp[k * DD + col];
    wf[g * 16384 + r] = f2bf(w);
  }
}

// ------- fused aggr + GEMM1 + stats (r16 structure) -------
__global__ __launch_bounds__(512) void k_aggemm(
    const unsigned short* __restrict__ in, const int* __restrict__ cnt,
    const unsigned short* __restrict__ bkt,
    const int* __restrict__ ovfc, const unsigned* __restrict__ ovf,
    const unsigned short* __restrict__ wf, const float* __restrict__ bias,
    unsigned short* __restrict__ outB, float* __restrict__ statsOut) {
  __shared__ __align__(16) short lw[16384];            // 32 KB W-hi frags
  __shared__ __align__(16) unsigned short hs[64 * HST];// 17 KB agg tile
  __shared__ float lbias[DD], ls[DD], lq[DD];
  int tid = threadIdx.x;
  int lane = tid & 63, wv = tid >> 6;
  int rbase = blockIdx.x * 64;

  {
    const float4* src = (const float4*)wf;
    float4* dst = (float4*)lw;
#pragma unroll
    for (int it = 0; it < 4; it++) dst[it * 512 + tid] = src[it * 512 + tid];
  }
  if (tid < DD) { lbias[tid] = bias[tid]; ls[tid] = 0.f; lq[tid] = 0.f; }

  // ---- phase 1: gather, 16 lanes/row ----
  {
    int l16 = tid & 15;
    const unsigned short* base = in + l16 * 8;
#pragma unroll
    for (int rep = 0; rep < 2; rep++) {
      int nl = (tid >> 4) + rep * 32;
      int node = rbase + nl;
      float a[8] = {0.f, 0.f, 0.f, 0.f, 0.f, 0.f, 0.f, 0.f};
      if (node < NN) {
        bf16x8 sv = *(const bf16x8*)(base + (size_t)node * DD);
#pragma unroll
        for (int i = 0; i < 8; i++) a[i] = bf2f((unsigned short)sv[i]);
        int cn = cnt[node];
        int ce = (cn < BSTRIDE) ? cn : BSTRIDE;
        const unsigned short* bp = bkt + (size_t)node * BSTRIDE;
        int j = 0;
        for (; j + 3 < ce; j += 4) {
          int s0 = bp[j], s1 = bp[j + 1], s2 = bp[j + 2], s3 = bp[j + 3];
          bf16x8 v0 = *(const bf16x8*)(base + (size_t)s0 * DD);
          bf16x8 v1 = *(const bf16x8*)(base + (size_t)s1 * DD);
          bf16x8 v2 = *(const bf16x8*)(base + (size_t)s2 * DD);
          bf16x8 v3 = *(const bf16x8*)(base + (size_t)s3 * DD);
#pragma unroll
          for (int i = 0; i < 8; i++)
            a[i] += bf2f((unsigned short)v0[i]) + bf2f((unsigned short)v1[i]) +
                    bf2f((unsigned short)v2[i]) + bf2f((unsigned short)v3[i]);
        }
        for (; j < ce; j++) {
          bf16x8 v0 = *(const bf16x8*)(base + (size_t)bp[j] * DD);
#pragma unroll
          for (int i = 0; i < 8; i++) a[i] += bf2f((unsigned short)v0[i]);
        }
        if (cn > BSTRIDE) {
          int no = ovfc[0];
          if (no > OVF_MAX) no = OVF_MAX;
          for (int o = 0; o < no; o++) {
            unsigned pr = ovf[o];
            if ((int)(pr >> 16) == node) {
              bf16x8 v0 = *(const bf16x8*)(base + (size_t)(pr & 0xFFFFu) * DD);
#pragma unroll
              for (int i = 0; i < 8; i++) a[i] += bf2f((unsigned short)v0[i]);
            }
          }
        }
      }
      bf16x8 hv;
#pragma unroll
      for (int i = 0; i < 8; i++) hv[i] = (short)f2bf(a[i]);
      *(bf16x8*)(&hs[nl * HST + l16 * 8]) = hv;
    }
  }
  __syncthreads();

  // ---- phase 2: GEMM ----
  int rblk = wv >> 1, ch = wv & 1;
  int kq = (lane >> 4) * 8;
  bf16x8 araw[4];
  {
    int lr = rblk * 16 + (lane & 15);
#pragma unroll
    for (int ks = 0; ks < 4; ks++)
      araw[ks] = *(const bf16x8*)(&hs[lr * HST + ks * 32 + kq]);
  }
  f32x4 acc[4];
#pragma unroll
  for (int ct = 0; ct < 4; ct++) acc[ct] = (f32x4){0.f, 0.f, 0.f, 0.f};
  const bf16x8* lwv = (const bf16x8*)lw;
#pragma unroll
  for (int ks = 0; ks < 4; ks++) {
#pragma unroll
    for (int ct = 0; ct < 4; ct++) {
      bf16x8 bh = lwv[((ch * 4 + ct) * 4 + ks) * 64 + lane];
      acc[ct] = __builtin_amdgcn_mfma_f32_16x16x32_bf16(araw[ks], bh, acc[ct], 0, 0, 0);
    }
  }

  {
    int r0 = rbase + rblk * 16 + (lane >> 4) * 4;
#pragma unroll
    for (int ct = 0; ct < 4; ct++) {
      int col = ch * 64 + ct * 16 + (lane & 15);
      float bb = lbias[col];
      float s = 0.f, q = 0.f;
#pragma unroll
      for (int j = 0; j < 4; j++) {
        int row = r0 + j;
        if (row < NN) {
          float v = acc[ct][j] + bb;
          outB[(size_t)row * DD + col] = f2bf(v);
          s += v; q += v * v;
        }
      }
      s += __shfl_xor(s, 16); s += __shfl_xor(s, 32);
      q += __shfl_xor(q, 16); q += __shfl_xor(q, 32);
      if ((lane >> 4) == 0) {
        atomicAdd(&ls[col], s);
        atomicAdd(&lq[col], q);
      }
    }
  }
  __syncthreads();
  if (tid < DD) {
    float* slot = statsOut + (blockIdx.x & (NSLOT - 1)) * 2 * DD;
    atomicAdd(&slot[tid], ls[tid]);
    atomicAdd(&slot[DD + tid], lq[tid]);
  }
}

// ------- MFMA GEMM: BN -> relu -> GEMM -> relu (conv1 GEMM2) ----------
__global__ __launch_bounds__(512) void k_mgemm2(
    const unsigned short* __restrict__ in, const unsigned short* __restrict__ wf,
    const float* __restrict__ bias, unsigned short* __restrict__ outB,
    const float* __restrict__ statsIn,
    const float* __restrict__ gamma, const float* __restrict__ beta) {
  __shared__ __align__(16) char smem[32768];
  __shared__ float scs[DD], shs[DD], lbias[DD];
  short* lw = (short*)smem;
  int tid = threadIdx.x;
  int lane = tid & 63, wv = tid >> 6;
  int rbase = blockIdx.x * 128 + wv * 16;
  int kq = (lane >> 4) * 8;

  bf16x8 araw[4];
  {
    int row = rbase + (lane & 15);
    bool v = row < NN;
    const unsigned short* ap = in + (size_t)row * DD + kq;
    bf16x8 zz = {0, 0, 0, 0, 0, 0, 0, 0};
#pragma unroll
    for (int ks = 0; ks < 4; ks++)
      araw[ks] = v ? *(const bf16x8*)(ap + ks * 32) : zz;
  }
  {
    const float4* src = (const float4*)wf;
    float4* dst = (float4*)lw;
#pragma unroll
    for (int it = 0; it < 4; it++) dst[it * 512 + tid] = src[it * 512 + tid];
  }
  if (tid < DD) {
    lbias[tid] = bias[tid];
    float su = 0.f, sq = 0.f;
#pragma unroll
    for (int s = 0; s < NSLOT; s++) {
      su += statsIn[s * 2 * DD + tid];
      sq += statsIn[s * 2 * DD + DD + tid];
    }
    float mu  = su * (1.0f / NN);
    float var = sq * (1.0f / NN) - mu * mu;
    float sc  = gamma[tid] * rsqrtf(var + BN_EPS_F);
    scs[tid] = sc;
    shs[tid] = beta[tid] - mu * sc;
  }
  __syncthreads();

  bf16x8 ahi[4];
#pragma unroll
  for (int ks = 0; ks < 4; ks++) {
    const float4* s4 = (const float4*)&scs[ks * 32 + kq];
    const float4* h4 = (const float4*)&shs[ks * 32 + kq];
    float4 sa = s4[0], sb = s4[1], ha = h4[0], hb = h4[1];
    float ss[8] = {sa.x, sa.y, sa.z, sa.w, sb.x, sb.y, sb.z, sb.w};
    float hh[8] = {ha.x, ha.y, ha.z, ha.w, hb.x, hb.y, hb.z, hb.w};
    bf16x8 h;
#pragma unroll
    for (int i = 0; i < 8; i++) {
      float xv = fmaxf(bf2f((unsigned short)araw[ks][i]) * ss[i] + hh[i], 0.f);
      h[i] = (short)f2bf(xv);
    }
    ahi[ks] = h;
  }

  f32x4 acc[8];
#pragma unroll
  for (int ct = 0; ct < 8; ct++) acc[ct] = (f32x4){0.f, 0.f, 0.f, 0.f};
  const bf16x8* lwv = (const bf16x8*)lw;
#pragma unroll
  for (int ks = 0; ks < 4; ks++) {
#pragma unroll
    for (int ct = 0; ct < 8; ct++) {
      bf16x8 bh = lwv[(ct * 4 + ks) * 64 + lane];
      acc[ct] = __builtin_amdgcn_mfma_f32_16x16x32_bf16(ahi[ks], bh, acc[ct], 0, 0, 0);
    }
  }

  int r0 = rbase + (lane >> 4) * 4;
#pragma unroll
  for (int ct = 0; ct < 8; ct++) {
    int col = ct * 16 + (lane & 15);
    float bb = lbias[col];
#pragma unroll
    for (int j = 0; j < 4; j++) {
      int row = r0 + j;
      if (row < NN) {
        float v = fmaxf(acc[ct][j] + bb, 0.f);
        outB[(size_t)row * DD + col] = f2bf(v);
      }
    }
  }
}

// ------- fused tail: BN -> GEMM(W2b) -> relu -> GEMM(Wl1) -> relu ->
//         GEMM(Wl2) -> log_softmax.  Entire chain row-local (r17).
// R1: W2b frags -> h2 tile (XOR-swz 128x128 bf16) -> h3 tile (same)
// R2: Wl1 frags -> Wl2 (20K f32)
__global__ __launch_bounds__(512) void k_tail2(
    const unsigned short* __restrict__ in, const unsigned short* __restrict__ wfA,
    const float* __restrict__ biasA, const float* __restrict__ statsIn,
    const float* __restrict__ gamma, const float* __restrict__ beta,
    const unsigned short* __restrict__ wfB, const float* __restrict__ biasB,
    const float* __restrict__ W2h, const float* __restrict__ b2h,
    float* __restrict__ outF) {
  __shared__ __align__(16) char R1[32768];
  __shared__ __align__(16) char R2[32768];
  __shared__ float scs[DD], shs[DD], lbA[DD], lbB[DD];
  int tid = threadIdx.x;
  int lane = tid & 63, wv = tid >> 6;
  int rbase = blockIdx.x * 128 + wv * 16;
  int kq = (lane >> 4) * 8;

  // A prefetch
  bf16x8 araw[4];
  {
    int row = rbase + (lane & 15);
    bool v = row < NN;
    const unsigned short* ap = in + (size_t)row * DD + kq;
    bf16x8 zz = {0, 0, 0, 0, 0, 0, 0, 0};
#pragma unroll
    for (int ks = 0; ks < 4; ks++)
      araw[ks] = v ? *(const bf16x8*)(ap + ks * 32) : zz;
  }
  // stage W2b->R1, Wl1->R2
  {
    const float4* s1 = (const float4*)wfA;
    const float4* s2 = (const float4*)wfB;
    float4* d1 = (float4*)R1;
    float4* d2 = (float4*)R2;
#pragma unroll
    for (int it = 0; it < 4; it++) {
      d1[it * 512 + tid] = s1[it * 512 + tid];
      d2[it * 512 + tid] = s2[it * 512 + tid];
    }
  }
  if (tid < DD) {
    lbA[tid] = biasA[tid];
    lbB[tid] = biasB[tid];
    float su = 0.f, sq = 0.f;
#pragma unroll
    for (int s = 0; s < NSLOT; s++) {
      su += statsIn[s * 2 * DD + tid];
      sq += statsIn[s * 2 * DD + DD + tid];
    }
    float mu  = su * (1.0f / NN);
    float var = sq * (1.0f / NN) - mu * mu;
    float sc  = gamma[tid] * rsqrtf(var + BN_EPS_F);
    scs[tid] = sc;
    shs[tid] = beta[tid] - mu * sc;
  }
  __syncthreads();

  // BN in-register
  bf16x8 ahi[4];
#pragma unroll
  for (int ks = 0; ks < 4; ks++) {
    const float4* s4 = (const float4*)&scs[ks * 32 + kq];
    const float4* h4 = (const float4*)&shs[ks * 32 + kq];
    float4 sa = s4[0], sb = s4[1], ha = h4[0], hb = h4[1];
    float ss[8] = {sa.x, sa.y, sa.z, sa.w, sb.x, sb.y, sb.z, sb.w};
    float hh[8] = {ha.x, ha.y, ha.z, ha.w, hb.x, hb.y, hb.z, hb.w};
    bf16x8 h;
#pragma unroll
    for (int i = 0; i < 8; i++) {
      float xv = fmaxf(bf2f((unsigned short)araw[ks][i]) * ss[i] + hh[i], 0.f);
      h[i] = (short)f2bf(xv);
    }
    ahi[ks] = h;
  }

  // GEMM2 (W2b in R1)
  f32x4 acc[8];
#pragma unroll
  for (int ct = 0; ct < 8; ct++) acc[ct] = (f32x4){0.f, 0.f, 0.f, 0.f};
  {
    const bf16x8* l1 = (const bf16x8*)R1;
#pragma unroll
    for (int ks = 0; ks < 4; ks++) {
#pragma unroll
      for (int ct = 0; ct < 8; ct++) {
        bf16x8 bh = l1[(ct * 4 + ks) * 64 + lane];
        acc[ct] = __builtin_amdgcn_mfma_f32_16x16x32_bf16(ahi[ks], bh, acc[ct], 0, 0, 0);
      }
    }
  }
  __syncthreads();   // all waves done reading W2b from R1

  // h2 = relu(acc + bA) -> R1 (swz)   C/D: col=lane&15, row=(lane>>4)*4+reg
  {
    int fr0 = (lane >> 4) * 4;
    int lr0 = wv * 16 + fr0;
#pragma unroll
    for (int ct = 0; ct < 8; ct++) {
      int col = ct * 16 + (lane & 15);
      float bb = lbA[col];
#pragma unroll
      for (int j = 0; j < 4; j++) {
        int r = lr0 + j;
        float v = fmaxf(acc[ct][j] + bb, 0.f);
        int byt = (r * 256 + col * 2) ^ ((r & 7) << 4);
        *(unsigned short*)(R1 + byt) = f2bf(v);
      }
    }
  }
  __syncthreads();

  // A2 from R1 (swz reads, 2-way-free)
  bf16x8 a2[4];
  {
    int lr = wv * 16 + (lane & 15);
#pragma unroll
    for (int ks = 0; ks < 4; ks++) {
      int byt = (lr * 256 + ks * 64 + kq * 2) ^ ((lr & 7) << 4);
      a2[ks] = *(const bf16x8*)(R1 + byt);
    }
  }
  // GEMM(Wl1 in R2)
  f32x4 ac3[8];
#pragma unroll
  for (int ct = 0; ct < 8; ct++) ac3[ct] = (f32x4){0.f, 0.f, 0.f, 0.f};
  {
    const bf16x8* l2 = (const bf16x8*)R2;
#pragma unroll
    for (int ks = 0; ks < 4; ks++) {
#pragma unroll
      for (int ct = 0; ct < 8; ct++) {
        bf16x8 bh = l2[(ct * 4 + ks) * 64 + lane];
        ac3[ct] = __builtin_amdgcn_mfma_f32_16x16x32_bf16(a2[ks], bh, ac3[ct], 0, 0, 0);
      }
    }
  }
  __syncthreads();   // done with h2 (R1) and Wl1 (R2)

  // h3 = relu(ac3 + bB) -> R1 (swz);  Wl2 -> R2
  {
    int fr0 = (lane >> 4) * 4;
    int lr0 = wv * 16 + fr0;
#pragma unroll
    for (int ct = 0; ct < 8; ct++) {
      int col = ct * 16 + (lane & 15);
      float bb = lbB[col];
#pragma unroll
      for (int j = 0; j < 4; j++) {
        int r = lr0 + j;
        float v = fmaxf(ac3[ct][j] + bb, 0.f);
        int byt = (r * 256 + col * 2) ^ ((r & 7) << 4);
        *(unsigned short*)(R1 + byt) = f2bf(v);
      }
    }
    const float4* W2g = (const float4*)W2h;
    float4* W2s4 = (float4*)R2;
#pragma unroll
    for (int it = 0; it < 3; it++) {
      int idx = it * 512 + tid;
      if (idx < 1280) W2s4[idx] = W2g[idx];
    }
  }
  __syncthreads();

  // per-row head: 4 threads/row, k interleaved
  int lrow = tid >> 2, q = tid & 3;
  int grow = blockIdx.x * 128 + lrow;
  const float* W2s = (const float*)R2;
  float av[40];
#pragma unroll
  for (int j = 0; j < 40; j++) av[j] = 0.f;
  for (int kk = 0; kk < 32; kk++) {
    int k = kk * 4 + q;
    int byt = (lrow * 256 + k * 2) ^ ((lrow & 7) << 4);
    float hv = bf2f(*(const unsigned short*)(R1 + byt));
    const float4* wrow = (const float4*)(W2s + k * DOUT);
#pragma unroll
    for (int j4 = 0; j4 < 10; j4++) {
      float4 w = wrow[j4];
      av[j4 * 4 + 0] += hv * w.x;
      av[j4 * 4 + 1] += hv * w.y;
      av[j4 * 4 + 2] += hv * w.z;
      av[j4 * 4 + 3] += hv * w.w;
    }
  }
#pragma unroll
  for (int j = 0; j < 40; j++) {
    av[j] += __shfl_xor(av[j], 1);
    av[j] += __shfl_xor(av[j], 2);
  }
  if (q == 0 && grow < NN) {
    const float4* b24 = (const float4*)b2h;
    float m = -INFINITY;
#pragma unroll
    for (int j4 = 0; j4 < 10; j4++) {
      float4 bb = b24[j4];
      av[j4 * 4 + 0] += bb.x; av[j4 * 4 + 1] += bb.y;
      av[j4 * 4 + 2] += bb.z; av[j4 * 4 + 3] += bb.w;
    }
#pragma unroll
    for (int j = 0; j < 40; j++) m = fmaxf(m, av[j]);
    float s = 0.f;
#pragma unroll
    for (int j = 0; j < 40; j++) s += expf(av[j] - m);
    float d = m + logf(s);
    float4* out4 = (float4*)(outF + (size_t)grow * DOUT);
#pragma unroll
    for (int j4 = 0; j4 < 10; j4++) {
      float4 v = make_float4(av[j4 * 4 + 0] - d, av[j4 * 4 + 1] - d,
                             av[j4 * 4 + 2] - d, av[j4 * 4 + 3] - d);
      out4[j4] = v;
    }
  }
}

extern "C" void kernel_launch(void* const* d_in, const int* in_sizes, int n_in,
                              void* d_out, int out_size, void* d_ws, size_t ws_size,
                              hipStream_t stream) {
  const float* x   = (const float*)d_in[0];
  const int*   ei  = (const int*)d_in[1];
  const float* W1a = (const float*)d_in[2];
  const float* b1a = (const float*)d_in[3];
  const float* g1  = (const float*)d_in[4];
  const float* be1 = (const float*)d_in[5];
  const float* W2a = (const float*)d_in[6];
  const float* b2a = (const float*)d_in[7];
  const float* W1b = (const float*)d_in[8];
  const float* b1b = (const float*)d_in[9];
  const float* g2  = (const float*)d_in[10];
  const float* be2 = (const float*)d_in[11];
  const float* W2b = (const float*)d_in[12];
  const float* b2b = (const float*)d_in[13];
  const float* Wl1 = (const float*)d_in[14];
  const float* bl1 = (const float*)d_in[15];
  const float* Wl2 = (const float*)d_in[16];
  const float* bl2 = (const float*)d_in[17];
  float* out = (float*)d_out;

  unsigned short* bufX = (unsigned short*)d_ws;           // N x 128 bf16
  unsigned short* bufA = bufX + (size_t)NN * DD;          // N x 128 bf16
  unsigned short* bufB = bufA + (size_t)NN * DD;          // N x 128 bf16
  float* stats1 = (float*)(bufB + (size_t)NN * DD);       // NSLOT x 256
  float* stats2 = stats1 + NSLOT * 2 * DD;                // NSLOT x 256
  int*   cnt    = (int*)(stats2 + NSLOT * 2 * DD);        // N
  int*   ovfc   = cnt + NN;                               // 4 (1 used)
  unsigned* ovf = (unsigned*)(ovfc + 4);                  // OVF_MAX
  unsigned short* bkt = (unsigned short*)(ovf + OVF_MAX); // N x BSTRIDE
  size_t wfOff = (((size_t)(bkt + (size_t)NN * BSTRIDE) - (size_t)d_ws) + 15) & ~(size_t)15;
  unsigned short* wfrag = (unsigned short*)((char*)d_ws + wfOff);   // 5 x 16384 bf16

  const int* srcI = ei;
  const int* dstI = ei + NE;

  dim3 blk(256);
  int gemmGrid = (NN + 127) / 128;                       // 391
  int agGrid   = (NN + 63) / 64;                         // 782
  int bpGrid   = BUCKET_BLOCKS + X2BF_BLOCKS + WPREP_BLOCKS;
  int zeroGrid = (NN + 255) / 256;

  // ---- setup ----
  k_zero<<<zeroGrid, blk, 0, stream>>>(cnt, stats1, ovfc);
  k_bucketprep<<<bpGrid, blk, 0, stream>>>(srcI, dstI, cnt, bkt, ovfc, ovf,
                                           (const float4*)x, (ushort4*)bufX,
                                           W1a, W2a, W1b, W2b, Wl1, wfrag);

  // ---- conv1 ----
  k_aggemm<<<agGrid, 512, 0, stream>>>(bufX, cnt, bkt, ovfc, ovf,
                                       wfrag + 0 * 16384, b1a, bufB, stats1);
  k_mgemm2<<<gemmGrid, 512, 0, stream>>>(bufB, wfrag + 1 * 16384, b2a, bufA,
                                         stats1, g1, be1);
  // ---- conv2 ----
  k_aggemm<<<agGrid, 512, 0, stream>>>(bufA, cnt, bkt, ovfc, ovf,
                                       wfrag + 2 * 16384, b1b, bufB, stats2);
  // ---- fused conv2-GEMM2 + head ----
  k_tail2<<<gemmGrid, 512, 0, stream>>>(bufB, wfrag + 3 * 16384, b2b,
                                        stats2, g2, be2,
                                        wfrag + 4 * 16384, bl1, Wl2, bl2, out);
}

// Round 18
// 164.901 us; speedup vs baseline: 1.1670x; 1.1024x over previous
//
#include <hip/hip_runtime.h>
#include <math.h>

#define NN 50000
#define NE 800000
#define DD 128
#define DOUT 40
#define BN_EPS_F 1e-5f
#define BSTRIDE 32           // bucket row = one 64B line; overflow list for deg>32
#define OVF_MAX 8192
#define NPX (NN / 8)         // 6250 nodes per XCD partition
#define EPB 1024             // edges per chunk: 4 edges/thread via int4
#define BUCKET_BLOCKS (((NE + EPB - 1) / EPB) * 8)   // 6256
#define X2BF_BLOCKS 6250
#define WPREP_BLOCKS ((5 * 16384 + 255) / 256)       // 320
#define NSLOT 8              // BN-stats contention shards
#define HST 136              // aggemm h-tile stride (ushorts)

typedef __attribute__((ext_vector_type(8))) short bf16x8;
typedef __attribute__((ext_vector_type(4))) float f32x4;

static __device__ __forceinline__ unsigned short f2bf(float f) {
  unsigned u = __float_as_uint(f);
  unsigned r = (u + 0x7FFFu + ((u >> 16) & 1u)) >> 16;
  return (unsigned short)r;
}
static __device__ __forceinline__ float bf2f(unsigned short u) {
  return __uint_as_float((unsigned)u << 16);
}

// ---------------- zero cnt + stats + overflow counter ----------------
__global__ void k_zero(int* __restrict__ cnt, float* __restrict__ stats,
                       int* __restrict__ ovfc) {
  int i = blockIdx.x * 256 + threadIdx.x;
  if (i < NN) cnt[i] = 0;
  if (i < 2 * NSLOT * 2 * DD) stats[i] = 0.f;
  if (i == 0) ovfc[0] = 0;
}

// ---- fused: XCD-partitioned bucket build | x->bf16 | weight frag shuffle ----
__global__ void k_bucketprep(const int* __restrict__ srcI, const int* __restrict__ dstI,
                             int* __restrict__ cnt, unsigned short* __restrict__ bkt,
                             int* __restrict__ ovfc, unsigned* __restrict__ ovf,
                             const float4* __restrict__ x, ushort4* __restrict__ xb,
                             const float* __restrict__ W0, const float* __restrict__ W1,
                             const float* __restrict__ W2, const float* __restrict__ W3,
                             const float* __restrict__ W4, unsigned short* __restrict__ wf) {
  int b = blockIdx.x;
  if (b < BUCKET_BLOCKS) {
    int xcd = b & 7;
    int chunk = b >> 3;
    int lo = xcd * NPX, hi = lo + NPX;
    int e0 = chunk * EPB + threadIdx.x * 4;
    if (e0 < NE) {
      int4 d4 = *(const int4*)(dstI + e0);
      int4 s4 = *(const int4*)(srcI + e0);
      int dd[4] = {d4.x, d4.y, d4.z, d4.w};
      int ss[4] = {s4.x, s4.y, s4.z, s4.w};
#pragma unroll
      for (int i = 0; i < 4; i++) {
        int d = dd[i];
        if (d >= lo && d < hi) {
          int r = atomicAdd(&cnt[d], 1);
          if (r < BSTRIDE) {
            bkt[(size_t)d * BSTRIDE + r] = (unsigned short)ss[i];
          } else {
            int o = atomicAdd(ovfc, 1);
            if (o < OVF_MAX) ovf[o] = ((unsigned)d << 16) | (unsigned)ss[i];
          }
        }
      }
    }
  } else if (b < BUCKET_BLOCKS + X2BF_BLOCKS) {
    int i = (b - BUCKET_BLOCKS) * 256 + threadIdx.x;
    if (i < NN * 32) {
      float4 v = x[i];
      ushort4 r;
      r.x = f2bf(v.x); r.y = f2bf(v.y); r.z = f2bf(v.z); r.w = f2bf(v.w);
      xb[i] = r;
    }
  } else {
    int fid = (b - BUCKET_BLOCKS - X2BF_BLOCKS) * 256 + threadIdx.x;
    if (fid >= 5 * 16384) return;
    int g = fid >> 14;
    int r = fid & 16383;
    int i = r & 7;
    int lane = (r >> 3) & 63;
    int ks = (r >> 9) & 3;
    int ct = r >> 11;
    int k = ks * 32 + (lane >> 4) * 8 + i;
    int col = ct * 16 + (lane & 15);
    const float* Wp = (g == 0) ? W0 : (g == 1) ? W1 : (g == 2) ? W2 : (g == 3) ? W3 : W4;
    float w = Wp[k * DD + col];
    wf[g * 16384 + r] = f2bf(w);
  }
}

// ------- fused aggr + GEMM1 + stats -------
// r18: no W LDS stage — phase-2 B-frags read straight from global wfrag (32 KB,
// L2-resident, same addrs across blocks). LDS ~19 KB -> 4 blocks/CU (wave cap),
// doubling resident waves for the latency-bound gather phase.
__global__ __launch_bounds__(512) void k_aggemm(
    const unsigned short* __restrict__ in, const int* __restrict__ cnt,
    const unsigned short* __restrict__ bkt,
    const int* __restrict__ ovfc, const unsigned* __restrict__ ovf,
    const unsigned short* __restrict__ wf, const float* __restrict__ bias,
    unsigned short* __restrict__ outB, float* __restrict__ statsOut) {
  __shared__ __align__(16) unsigned short hs[64 * HST];  // 17.4 KB agg tile
  __shared__ float lbias[DD], ls[DD], lq[DD];
  int tid = threadIdx.x;
  int lane = tid & 63, wv = tid >> 6;
  int rbase = blockIdx.x * 64;

  if (tid < DD) { lbias[tid] = bias[tid]; ls[tid] = 0.f; lq[tid] = 0.f; }

  // ---- phase 1: gather, 16 lanes/row ----
  {
    int l16 = tid & 15;
    const unsigned short* base = in + l16 * 8;
#pragma unroll
    for (int rep = 0; rep < 2; rep++) {
      int nl = (tid >> 4) + rep * 32;
      int node = rbase + nl;
      float a[8] = {0.f, 0.f, 0.f, 0.f, 0.f, 0.f, 0.f, 0.f};
      if (node < NN) {
        bf16x8 sv = *(const bf16x8*)(base + (size_t)node * DD);
#pragma unroll
        for (int i = 0; i < 8; i++) a[i] = bf2f((unsigned short)sv[i]);
        int cn = cnt[node];
        int ce = (cn < BSTRIDE) ? cn : BSTRIDE;
        const unsigned short* bp = bkt + (size_t)node * BSTRIDE;
        int j = 0;
        for (; j + 3 < ce; j += 4) {
          int s0 = bp[j], s1 = bp[j + 1], s2 = bp[j + 2], s3 = bp[j + 3];
          bf16x8 v0 = *(const bf16x8*)(base + (size_t)s0 * DD);
          bf16x8 v1 = *(const bf16x8*)(base + (size_t)s1 * DD);
          bf16x8 v2 = *(const bf16x8*)(base + (size_t)s2 * DD);
          bf16x8 v3 = *(const bf16x8*)(base + (size_t)s3 * DD);
#pragma unroll
          for (int i = 0; i < 8; i++)
            a[i] += bf2f((unsigned short)v0[i]) + bf2f((unsigned short)v1[i]) +
                    bf2f((unsigned short)v2[i]) + bf2f((unsigned short)v3[i]);
        }
        for (; j < ce; j++) {
          bf16x8 v0 = *(const bf16x8*)(base + (size_t)bp[j] * DD);
#pragma unroll
          for (int i = 0; i < 8; i++) a[i] += bf2f((unsigned short)v0[i]);
        }
        if (cn > BSTRIDE) {
          int no = ovfc[0];
          if (no > OVF_MAX) no = OVF_MAX;
          for (int o = 0; o < no; o++) {
            unsigned pr = ovf[o];
            if ((int)(pr >> 16) == node) {
              bf16x8 v0 = *(const bf16x8*)(base + (size_t)(pr & 0xFFFFu) * DD);
#pragma unroll
              for (int i = 0; i < 8; i++) a[i] += bf2f((unsigned short)v0[i]);
            }
          }
        }
      }
      bf16x8 hv;
#pragma unroll
      for (int i = 0; i < 8; i++) hv[i] = (short)f2bf(a[i]);
      *(bf16x8*)(&hs[nl * HST + l16 * 8]) = hv;
    }
  }
  __syncthreads();

  // ---- phase 2: GEMM, B-frags from global (L2-hit) ----
  int rblk = wv >> 1, ch = wv & 1;
  int kq = (lane >> 4) * 8;
  bf16x8 araw[4];
  {
    int lr = rblk * 16 + (lane & 15);
#pragma unroll
    for (int ks = 0; ks < 4; ks++)
      araw[ks] = *(const bf16x8*)(&hs[lr * HST + ks * 32 + kq]);
  }
  f32x4 acc[4];
#pragma unroll
  for (int ct = 0; ct < 4; ct++) acc[ct] = (f32x4){0.f, 0.f, 0.f, 0.f};
  const bf16x8* gw = (const bf16x8*)wf;
#pragma unroll
  for (int ks = 0; ks < 4; ks++) {
#pragma unroll
    for (int ct = 0; ct < 4; ct++) {
      bf16x8 bh = gw[((ch * 4 + ct) * 4 + ks) * 64 + lane];
      acc[ct] = __builtin_amdgcn_mfma_f32_16x16x32_bf16(araw[ks], bh, acc[ct], 0, 0, 0);
    }
  }

  {
    int r0 = rbase + rblk * 16 + (lane >> 4) * 4;
#pragma unroll
    for (int ct = 0; ct < 4; ct++) {
      int col = ch * 64 + ct * 16 + (lane & 15);
      float bb = lbias[col];
      float s = 0.f, q = 0.f;
#pragma unroll
      for (int j = 0; j < 4; j++) {
        int row = r0 + j;
        if (row < NN) {
          float v = acc[ct][j] + bb;
          outB[(size_t)row * DD + col] = f2bf(v);
          s += v; q += v * v;
        }
      }
      s += __shfl_xor(s, 16); s += __shfl_xor(s, 32);
      q += __shfl_xor(q, 16); q += __shfl_xor(q, 32);
      if ((lane >> 4) == 0) {
        atomicAdd(&ls[col], s);
        atomicAdd(&lq[col], q);
      }
    }
  }
  __syncthreads();
  if (tid < DD) {
    float* slot = statsOut + (blockIdx.x & (NSLOT - 1)) * 2 * DD;
    atomicAdd(&slot[tid], ls[tid]);
    atomicAdd(&slot[DD + tid], lq[tid]);
  }
}

// ------- MFMA GEMM: BN -> relu -> GEMM -> relu (conv1 GEMM2) ----------
__global__ __launch_bounds__(512) void k_mgemm2(
    const unsigned short* __restrict__ in, const unsigned short* __restrict__ wf,
    const float* __restrict__ bias, unsigned short* __restrict__ outB,
    const float* __restrict__ statsIn,
    const float* __restrict__ gamma, const float* __restrict__ beta) {
  __shared__ __align__(16) char smem[32768];
  __shared__ float scs[DD], shs[DD], lbias[DD];
  short* lw = (short*)smem;
  int tid = threadIdx.x;
  int lane = tid & 63, wv = tid >> 6;
  int rbase = blockIdx.x * 128 + wv * 16;
  int kq = (lane >> 4) * 8;

  bf16x8 araw[4];
  {
    int row = rbase + (lane & 15);
    bool v = row < NN;
    const unsigned short* ap = in + (size_t)row * DD + kq;
    bf16x8 zz = {0, 0, 0, 0, 0, 0, 0, 0};
#pragma unroll
    for (int ks = 0; ks < 4; ks++)
      araw[ks] = v ? *(const bf16x8*)(ap + ks * 32) : zz;
  }
  {
    const float4* src = (const float4*)wf;
    float4* dst = (float4*)lw;
#pragma unroll
    for (int it = 0; it < 4; it++) dst[it * 512 + tid] = src[it * 512 + tid];
  }
  if (tid < DD) {
    lbias[tid] = bias[tid];
    float su = 0.f, sq = 0.f;
#pragma unroll
    for (int s = 0; s < NSLOT; s++) {
      su += statsIn[s * 2 * DD + tid];
      sq += statsIn[s * 2 * DD + DD + tid];
    }
    float mu  = su * (1.0f / NN);
    float var = sq * (1.0f / NN) - mu * mu;
    float sc  = gamma[tid] * rsqrtf(var + BN_EPS_F);
    scs[tid] = sc;
    shs[tid] = beta[tid] - mu * sc;
  }
  __syncthreads();

  bf16x8 ahi[4];
#pragma unroll
  for (int ks = 0; ks < 4; ks++) {
    const float4* s4 = (const float4*)&scs[ks * 32 + kq];
    const float4* h4 = (const float4*)&shs[ks * 32 + kq];
    float4 sa = s4[0], sb = s4[1], ha = h4[0], hb = h4[1];
    float ss[8] = {sa.x, sa.y, sa.z, sa.w, sb.x, sb.y, sb.z, sb.w};
    float hh[8] = {ha.x, ha.y, ha.z, ha.w, hb.x, hb.y, hb.z, hb.w};
    bf16x8 h;
#pragma unroll
    for (int i = 0; i < 8; i++) {
      float xv = fmaxf(bf2f((unsigned short)araw[ks][i]) * ss[i] + hh[i], 0.f);
      h[i] = (short)f2bf(xv);
    }
    ahi[ks] = h;
  }

  f32x4 acc[8];
#pragma unroll
  for (int ct = 0; ct < 8; ct++) acc[ct] = (f32x4){0.f, 0.f, 0.f, 0.f};
  const bf16x8* lwv = (const bf16x8*)lw;
#pragma unroll
  for (int ks = 0; ks < 4; ks++) {
#pragma unroll
    for (int ct = 0; ct < 8; ct++) {
      bf16x8 bh = lwv[(ct * 4 + ks) * 64 + lane];
      acc[ct] = __builtin_amdgcn_mfma_f32_16x16x32_bf16(ahi[ks], bh, acc[ct], 0, 0, 0);
    }
  }

  int r0 = rbase + (lane >> 4) * 4;
#pragma unroll
  for (int ct = 0; ct < 8; ct++) {
    int col = ct * 16 + (lane & 15);
    float bb = lbias[col];
#pragma unroll
    for (int j = 0; j < 4; j++) {
      int row = r0 + j;
      if (row < NN) {
        float v = fmaxf(acc[ct][j] + bb, 0.f);
        outB[(size_t)row * DD + col] = f2bf(v);
      }
    }
  }
}

// ------- fused tail: BN -> GEMM(W2b) -> relu -> GEMM(Wl1) -> relu ->
//         GEMM(Wl2) -> log_softmax (r17 structure) -------
__global__ __launch_bounds__(512) void k_tail2(
    const unsigned short* __restrict__ in, const unsigned short* __restrict__ wfA,
    const float* __restrict__ biasA, const float* __restrict__ statsIn,
    const float* __restrict__ gamma, const float* __restrict__ beta,
    const unsigned short* __restrict__ wfB, const float* __restrict__ biasB,
    const float* __restrict__ W2h, const float* __restrict__ b2h,
    float* __restrict__ outF) {
  __shared__ __align__(16) char R1[32768];
  __shared__ __align__(16) char R2[32768];
  __shared__ float scs[DD], shs[DD], lbA[DD], lbB[DD];
  int tid = threadIdx.x;
  int lane = tid & 63, wv = tid >> 6;
  int rbase = blockIdx.x * 128 + wv * 16;
  int kq = (lane >> 4) * 8;

  bf16x8 araw[4];
  {
    int row = rbase + (lane & 15);
    bool v = row < NN;
    const unsigned short* ap = in + (size_t)row * DD + kq;
    bf16x8 zz = {0, 0, 0, 0, 0, 0, 0, 0};
#pragma unroll
    for (int ks = 0; ks < 4; ks++)
      araw[ks] = v ? *(const bf16x8*)(ap + ks * 32) : zz;
  }
  {
    const float4* s1 = (const float4*)wfA;
    const float4* s2 = (const float4*)wfB;
    float4* d1 = (float4*)R1;
    float4* d2 = (float4*)R2;
#pragma unroll
    for (int it = 0; it < 4; it++) {
      d1[it * 512 + tid] = s1[it * 512 + tid];
      d2[it * 512 + tid] = s2[it * 512 + tid];
    }
  }
  if (tid < DD) {
    lbA[tid] = biasA[tid];
    lbB[tid] = biasB[tid];
    float su = 0.f, sq = 0.f;
#pragma unroll
    for (int s = 0; s < NSLOT; s++) {
      su += statsIn[s * 2 * DD + tid];
      sq += statsIn[s * 2 * DD + DD + tid];
    }
    float mu  = su * (1.0f / NN);
    float var = sq * (1.0f / NN) - mu * mu;
    float sc  = gamma[tid] * rsqrtf(var + BN_EPS_F);
    scs[tid] = sc;
    shs[tid] = beta[tid] - mu * sc;
  }
  __syncthreads();

  bf16x8 ahi[4];
#pragma unroll
  for (int ks = 0; ks < 4; ks++) {
    const float4* s4 = (const float4*)&scs[ks * 32 + kq];
    const float4* h4 = (const float4*)&shs[ks * 32 + kq];
    float4 sa = s4[0], sb = s4[1], ha = h4[0], hb = h4[1];
    float ss[8] = {sa.x, sa.y, sa.z, sa.w, sb.x, sb.y, sb.z, sb.w};
    float hh[8] = {ha.x, ha.y, ha.z, ha.w, hb.x, hb.y, hb.z, hb.w};
    bf16x8 h;
#pragma unroll
    for (int i = 0; i < 8; i++) {
      float xv = fmaxf(bf2f((unsigned short)araw[ks][i]) * ss[i] + hh[i], 0.f);
      h[i] = (short)f2bf(xv);
    }
    ahi[ks] = h;
  }

  f32x4 acc[8];
#pragma unroll
  for (int ct = 0; ct < 8; ct++) acc[ct] = (f32x4){0.f, 0.f, 0.f, 0.f};
  {
    const bf16x8* l1 = (const bf16x8*)R1;
#pragma unroll
    for (int ks = 0; ks < 4; ks++) {
#pragma unroll
      for (int ct = 0; ct < 8; ct++) {
        bf16x8 bh = l1[(ct * 4 + ks) * 64 + lane];
        acc[ct] = __builtin_amdgcn_mfma_f32_16x16x32_bf16(ahi[ks], bh, acc[ct], 0, 0, 0);
      }
    }
  }
  __syncthreads();

  {
    int fr0 = (lane >> 4) * 4;
    int lr0 = wv * 16 + fr0;
#pragma unroll
    for (int ct = 0; ct < 8; ct++) {
      int col = ct * 16 + (lane & 15);
      float bb = lbA[col];
#pragma unroll
      for (int j = 0; j < 4; j++) {
        int r = lr0 + j;
        float v = fmaxf(acc[ct][j] + bb, 0.f);
        int byt = (r * 256 + col * 2) ^ ((r & 7) << 4);
        *(unsigned short*)(R1 + byt) = f2bf(v);
      }
    }
  }
  __syncthreads();

  bf16x8 a2[4];
  {
    int lr = wv * 16 + (lane & 15);
#pragma unroll
    for (int ks = 0; ks < 4; ks++) {
      int byt = (lr * 256 + ks * 64 + kq * 2) ^ ((lr & 7) << 4);
      a2[ks] = *(const bf16x8*)(R1 + byt);
    }
  }
  f32x4 ac3[8];
#pragma unroll
  for (int ct = 0; ct < 8; ct++) ac3[ct] = (f32x4){0.f, 0.f, 0.f, 0.f};
  {
    const bf16x8* l2 = (const bf16x8*)R2;
#pragma unroll
    for (int ks = 0; ks < 4; ks++) {
#pragma unroll
      for (int ct = 0; ct < 8; ct++) {
        bf16x8 bh = l2[(ct * 4 + ks) * 64 + lane];
        ac3[ct] = __builtin_amdgcn_mfma_f32_16x16x32_bf16(a2[ks], bh, ac3[ct], 0, 0, 0);
      }
    }
  }
  __syncthreads();

  {
    int fr0 = (lane >> 4) * 4;
    int lr0 = wv * 16 + fr0;
#pragma unroll
    for (int ct = 0; ct < 8; ct++) {
      int col = ct * 16 + (lane & 15);
      float bb = lbB[col];
#pragma unroll
      for (int j = 0; j < 4; j++) {
        int r = lr0 + j;
        float v = fmaxf(ac3[ct][j] + bb, 0.f);
        int byt = (r * 256 + col * 2) ^ ((r & 7) << 4);
        *(unsigned short*)(R1 + byt) = f2bf(v);
      }
    }
    const float4* W2g = (const float4*)W2h;
    float4* W2s4 = (float4*)R2;
#pragma unroll
    for (int it = 0; it < 3; it++) {
      int idx = it * 512 + tid;
      if (idx < 1280) W2s4[idx] = W2g[idx];
    }
  }
  __syncthreads();

  int lrow = tid >> 2, q = tid & 3;
  int grow = blockIdx.x * 128 + lrow;
  const float* W2s = (const float*)R2;
  float av[40];
#pragma unroll
  for (int j = 0; j < 40; j++) av[j] = 0.f;
  for (int kk = 0; kk < 32; kk++) {
    int k = kk * 4 + q;
    int byt = (lrow * 256 + k * 2) ^ ((lrow & 7) << 4);
    float hv = bf2f(*(const unsigned short*)(R1 + byt));
    const float4* wrow = (const float4*)(W2s + k * DOUT);
#pragma unroll
    for (int j4 = 0; j4 < 10; j4++) {
      float4 w = wrow[j4];
      av[j4 * 4 + 0] += hv * w.x;
      av[j4 * 4 + 1] += hv * w.y;
      av[j4 * 4 + 2] += hv * w.z;
      av[j4 * 4 + 3] += hv * w.w;
    }
  }
#pragma unroll
  for (int j = 0; j < 40; j++) {
    av[j] += __shfl_xor(av[j], 1);
    av[j] += __shfl_xor(av[j], 2);
  }
  if (q == 0 && grow < NN) {
    const float4* b24 = (const float4*)b2h;
    float m = -INFINITY;
#pragma unroll
    for (int j4 = 0; j4 < 10; j4++) {
      float4 bb = b24[j4];
      av[j4 * 4 + 0] += bb.x; av[j4 * 4 + 1] += bb.y;
      av[j4 * 4 + 2] += bb.z; av[j4 * 4 + 3] += bb.w;
    }
#pragma unroll
    for (int j = 0; j < 40; j++) m = fmaxf(m, av[j]);
    float s = 0.f;
#pragma unroll
    for (int j = 0; j < 40; j++) s += expf(av[j] - m);
    float d = m + logf(s);
    float4* out4 = (float4*)(outF + (size_t)grow * DOUT);
#pragma unroll
    for (int j4 = 0; j4 < 10; j4++) {
      float4 v = make_float4(av[j4 * 4 + 0] - d, av[j4 * 4 + 1] - d,
                             av[j4 * 4 + 2] - d, av[j4 * 4 + 3] - d);
      out4[j4] = v;
    }
  }
}

extern "C" void kernel_launch(void* const* d_in, const int* in_sizes, int n_in,
                              void* d_out, int out_size, void* d_ws, size_t ws_size,
                              hipStream_t stream) {
  const float* x   = (const float*)d_in[0];
  const int*   ei  = (const int*)d_in[1];
  const float* W1a = (const float*)d_in[2];
  const float* b1a = (const float*)d_in[3];
  const float* g1  = (const float*)d_in[4];
  const float* be1 = (const float*)d_in[5];
  const float* W2a = (const float*)d_in[6];
  const float* b2a = (const float*)d_in[7];
  const float* W1b = (const float*)d_in[8];
  const float* b1b = (const float*)d_in[9];
  const float* g2  = (const float*)d_in[10];
  const float* be2 = (const float*)d_in[11];
  const float* W2b = (const float*)d_in[12];
  const float* b2b = (const float*)d_in[13];
  const float* Wl1 = (const float*)d_in[14];
  const float* bl1 = (const float*)d_in[15];
  const float* Wl2 = (const float*)d_in[16];
  const float* bl2 = (const float*)d_in[17];
  float* out = (float*)d_out;

  unsigned short* bufX = (unsigned short*)d_ws;           // N x 128 bf16
  unsigned short* bufA = bufX + (size_t)NN * DD;          // N x 128 bf16
  unsigned short* bufB = bufA + (size_t)NN * DD;          // N x 128 bf16
  float* stats1 = (float*)(bufB + (size_t)NN * DD);       // NSLOT x 256
  float* stats2 = stats1 + NSLOT * 2 * DD;                // NSLOT x 256
  int*   cnt    = (int*)(stats2 + NSLOT * 2 * DD);        // N
  int*   ovfc   = cnt + NN;                               // 4 (1 used)
  unsigned* ovf = (unsigned*)(ovfc + 4);                  // OVF_MAX
  unsigned short* bkt = (unsigned short*)(ovf + OVF_MAX); // N x BSTRIDE
  size_t wfOff = (((size_t)(bkt + (size_t)NN * BSTRIDE) - (size_t)d_ws) + 15) & ~(size_t)15;
  unsigned short* wfrag = (unsigned short*)((char*)d_ws + wfOff);   // 5 x 16384 bf16

  const int* srcI = ei;
  const int* dstI = ei + NE;

  dim3 blk(256);
  int gemmGrid = (NN + 127) / 128;                       // 391
  int agGrid   = (NN + 63) / 64;                         // 782
  int bpGrid   = BUCKET_BLOCKS + X2BF_BLOCKS + WPREP_BLOCKS;
  int zeroGrid = (NN + 255) / 256;

  // ---- setup ----
  k_zero<<<zeroGrid, blk, 0, stream>>>(cnt, stats1, ovfc);
  k_bucketprep<<<bpGrid, blk, 0, stream>>>(srcI, dstI, cnt, bkt, ovfc, ovf,
                                           (const float4*)x, (ushort4*)bufX,
                                           W1a, W2a, W1b, W2b, Wl1, wfrag);

  // ---- conv1 ----
  k_aggemm<<<agGrid, 512, 0, stream>>>(bufX, cnt, bkt, ovfc, ovf,
                                       wfrag + 0 * 16384, b1a, bufB, stats1);
  k_mgemm2<<<gemmGrid, 512, 0, stream>>>(bufB, wfrag + 1 * 16384, b2a, bufA,
                                         stats1, g1, be1);
  // ---- conv2 ----
  k_aggemm<<<agGrid, 512, 0, stream>>>(bufA, cnt, bkt, ovfc, ovf,
                                       wfrag + 2 * 16384, b1b, bufB, stats2);
  // ---- fused conv2-GEMM2 + head ----
  k_tail2<<<gemmGrid, 512, 0, stream>>>(bufB, wfrag + 3 * 16384, b2b,
                                        stats2, g2, be2,
                                        wfrag + 4 * 16384, bl1, Wl2, bl2, out);
}